// Round 1
// baseline (122.748 us; speedup 1.0000x reference)
//
#include <hip/hip_runtime.h>
#include <hip/hip_fp16.h>
#include <math.h>

#define HH 8
#define WW 32
#define HW 256
#define NN 20
#define FF 128
#define LL 1024
#define AA 360
#define CO 64

// workspace offsets (in floats)
#define OFF_LPANO      (AA*HW)
#define OFF_OV(B)      (OFF_LPANO + (B)*NN*HW)
#define OFF_SCAL(B)    (OFF_OV(B) + (B)*LL*2)
#define OFF_BASE(B)    (OFF_SCAL(B) + 8)
#define OFF_IDX(B)     (OFF_BASE(B) + (B)*LL*NN)

// ---------------------------------------------------------------------------
// K1: precompute Lray[360][256], Lpano[B*20][256], ov_stats[B*1024][2], scalars
// ---------------------------------------------------------------------------
__global__ __launch_bounds__(256)
void k1_pre(const float* __restrict__ rays, const float* __restrict__ feats,
            const float* __restrict__ overhead,
            const float* __restrict__ W1, const float* __restrict__ b1,
            const float* __restrict__ W2, const float* __restrict__ b2,
            const float* __restrict__ Wf, const float* __restrict__ bfp,
            float* __restrict__ ws, int B)
{
    const int bid = blockIdx.x, tid = threadIdx.x;
    const float wf0 = Wf[0], wf1 = Wf[1];

    if (bid < AA) {                       // ---- Lray for angle bid
        __shared__ float s[3*HW];
        for (int c = 0; c < 3; ++c) s[c*HW + tid] = rays[(bid*3 + c)*HW + tid];
        __syncthreads();
        const int h = tid >> 5, w = tid & 31;
        float c1 = 0.f, c2 = 0.f;
        #pragma unroll
        for (int c = 0; c < 3; ++c) {
            #pragma unroll
            for (int ky = 0; ky < 3; ++ky)
                #pragma unroll
                for (int kx = 0; kx < 3; ++kx)
                    c1 += W1[(1+c)*9 + ky*3 + kx] *
                          s[c*HW + (((h+ky+7)&7)<<5) + ((w+kx+31)&31)];
            #pragma unroll
            for (int ky = 0; ky < 5; ++ky)
                #pragma unroll
                for (int kx = 0; kx < 5; ++kx)
                    c2 += W2[(1+c)*25 + ky*5 + kx] *
                          s[c*HW + (((h+ky+6)&7)<<5) + ((w+kx+30)&31)];
        }
        ws[bid*HW + tid] = wf0*c1 + wf1*c2;
        return;
    }

    const int pb = bid - AA;
    if (pb < B*NN) {                      // ---- pano stats + conv -> Lpano
        __shared__ float p[2*HW];
        const float* fp = feats + (size_t)pb * FF * HW + tid;
        float mx = -INFINITY; double sm = 0.0;
        for (int f = 0; f < FF; ++f) {
            float v = fp[(size_t)f * HW];
            mx = fmaxf(mx, v); sm += (double)v;
        }
        p[tid]      = mx;
        p[HW + tid] = (float)(sm / 128.0);
        __syncthreads();
        const int h = tid >> 5, w = tid & 31;
        float c1 = 0.f, c2 = 0.f;
        #pragma unroll
        for (int c = 0; c < 2; ++c) {
            #pragma unroll
            for (int ky = 0; ky < 3; ++ky)
                #pragma unroll
                for (int kx = 0; kx < 3; ++kx)
                    c1 += W1[(4+c)*9 + ky*3 + kx] *
                          p[c*HW + (((h+ky+7)&7)<<5) + ((w+kx+31)&31)];
            #pragma unroll
            for (int ky = 0; ky < 5; ++ky)
                #pragma unroll
                for (int kx = 0; kx < 5; ++kx)
                    c2 += W2[(4+c)*25 + ky*5 + kx] *
                          p[c*HW + (((h+ky+6)&7)<<5) + ((w+kx+30)&31)];
        }
        ws[OFF_LPANO + pb*HW + tid] = wf0*c1 + wf1*c2;
        return;
    }

    const int ob = bid - AA - B*NN;
    if (ob < B*4) {                       // ---- overhead stats
        const int t = ob*256 + tid;       // t in [0, B*1024)
        const int b = t >> 10, l = t & 1023;
        const float* op = overhead + (size_t)b*CO*LL + l;
        float mx = -INFINITY; double sm = 0.0;
        for (int c = 0; c < CO; ++c) {
            float v = op[(size_t)c*LL];
            mx = fmaxf(mx, v); sm += (double)v;
        }
        ws[OFF_OV(B) + t*2]     = mx;
        ws[OFF_OV(B) + t*2 + 1] = (float)(sm / 64.0);
        return;
    }

    if (tid == 0) {                       // ---- scalar kernel-sums
        double s10=0, s16=0, s17=0, s20=0, s26=0, s27=0;
        for (int i = 0; i < 9;  ++i) { s10 += W1[i]; s16 += W1[54+i];  s17 += W1[63+i]; }
        for (int i = 0; i < 25; ++i) { s20 += W2[i]; s26 += W2[150+i]; s27 += W2[175+i]; }
        ws[OFF_SCAL(B)+0] = (float)(wf0*s10 + wf1*s20);            // Cd
        ws[OFF_SCAL(B)+1] = (float)(wf0*s16 + wf1*s26);            // Com
        ws[OFF_SCAL(B)+2] = (float)(wf0*s17 + wf1*s27);            // Cov
        ws[OFF_SCAL(B)+3] = wf0*b1[0] + wf1*b2[0] + bfp[0];        // Cb
    }
}

// ---------------------------------------------------------------------------
// K2: geometry (double, matches np f64 ref) -> idx[b,l,n], base[b,l,n]
// ---------------------------------------------------------------------------
__global__ __launch_bounds__(256)
void k2_geom(const float* __restrict__ bbox, const float* __restrict__ locs,
             float* __restrict__ ws, int B)
{
    const int t = blockIdx.x*256 + threadIdx.x;
    if (t >= B*LL*NN) return;
    const int b = t / (LL*NN), r = t % (LL*NN), l = r / NN, n = r % NN;
    const int iy = l >> 5, ix = l & 31;
    const double y0 = (double)bbox[b*4+0], x0 = (double)bbox[b*4+1];
    const double y1 = (double)bbox[b*4+2], x1 = (double)bbox[b*4+3];
    const double cy = y0 + (double)iy * (y1 - y0) / 31.0;
    const double cx = x0 + (double)ix * (x1 - x0) / 31.0;
    const double d0 = (double)locs[(b*NN+n)*2+0] - cy;
    const double d1 = (double)locs[(b*NN+n)*2+1] - cx;
    const double D  = sqrt(d0*d0 + d1*d1);
    double th = atan2(d1, d0);
    const double TWO_PI = 6.283185307179586476925286766559;
    th -= TWO_PI * floor(th / TWO_PI);                 // jnp.mod semantics
    const double deg = th * 57.295779513082320876798154814105;  // 180/pi
    int k = (int)llrint(deg);                          // round-half-even
    int idx = k % 360; if (idx < 0) idx += 360;

    const float Cd  = ws[OFF_SCAL(B)+0], Com = ws[OFF_SCAL(B)+1];
    const float Cov = ws[OFF_SCAL(B)+2], Cb  = ws[OFF_SCAL(B)+3];
    const int bl = b*LL + l;
    const float bv = (float)(Cd * D) + Com*ws[OFF_OV(B)+bl*2]
                   + Cov*ws[OFF_OV(B)+bl*2+1] + Cb;
    ws[OFF_BASE(B) + t] = bv;
    ((int*)(ws + OFF_IDX(B)))[t] = idx;
}

// ---------------------------------------------------------------------------
// K3: per-(b,l) softmax over (n,h,w), write weight output
// ---------------------------------------------------------------------------
__global__ __launch_bounds__(256)
void k3_softmax(const float* __restrict__ ws, float* __restrict__ out, int B)
{
    const int bid = blockIdx.x, tid = threadIdx.x;
    const int b = bid / LL;
    const float* Lray  = ws;
    const float* Lpano = ws + OFF_LPANO;
    const float* base  = ws + OFF_BASE(B) + (size_t)bid*NN;
    const int*   idxp  = (const int*)(ws + OFF_IDX(B)) + (size_t)bid*NN;

    __shared__ float sb[NN];
    __shared__ int   si[NN];
    __shared__ float sred[8];
    if (tid < NN) { sb[tid] = base[tid]; si[tid] = idxp[tid]; }
    __syncthreads();

    float lg[NN];
    float mx = -INFINITY;
    #pragma unroll
    for (int n = 0; n < NN; ++n) {
        lg[n] = sb[n] + Lray[si[n]*HW + tid] + Lpano[(b*NN+n)*HW + tid];
        mx = fmaxf(mx, lg[n]);
    }
    #pragma unroll
    for (int o = 32; o > 0; o >>= 1) mx = fmaxf(mx, __shfl_xor(mx, o, 64));
    if ((tid & 63) == 0) sred[tid >> 6] = mx;
    __syncthreads();
    mx = fmaxf(fmaxf(sred[0], sred[1]), fmaxf(sred[2], sred[3]));

    float sm = 0.f;
    #pragma unroll
    for (int n = 0; n < NN; ++n) { lg[n] = expf(lg[n] - mx); sm += lg[n]; }
    #pragma unroll
    for (int o = 32; o > 0; o >>= 1) sm += __shfl_xor(sm, o, 64);
    if ((tid & 63) == 0) sred[4 + (tid >> 6)] = sm;
    __syncthreads();
    const float inv = 1.0f / (sred[4] + sred[5] + sred[6] + sred[7]);

    float* wout = out + (size_t)B*LL*FF + (size_t)bid*NN*HW + tid;
    #pragma unroll
    for (int n = 0; n < NN; ++n) wout[n*HW] = lg[n] * inv;
}

// ---------------------------------------------------------------------------
// K4: grid_feats[b,l,f] = sum_{n,hw} weight * feats   (4 l-rows per block)
// ---------------------------------------------------------------------------
__global__ __launch_bounds__(256)
void k4_einsum(const float* __restrict__ feats, const float* __restrict__ wbuf,
               float* __restrict__ gout, int B)
{
    __shared__ __half wl[NN*HW*4];     // [n][hw][l4]  40 KB
    __shared__ float  red[64*20];      // 5 KB (stride 20 = 16 vals + pad)
    __shared__ float  red2[256];       // 1 KB
    const int bid = blockIdx.x, tid = threadIdx.x;
    const int b = bid >> 8, lb = bid & 255;   // 256 blocks per batch
    const int l0 = lb << 2;

    // stage weights (f32 -> f16) into LDS, coalesced reads
    for (int i = 0; i < 80; ++i) {
        const int flat = i*256 + tid;           // l4*5120 + n*256 + hw
        const int l4 = flat / 5120;
        const int rem = flat - l4*5120;
        const float v = wbuf[(size_t)(b*LL + l0 + l4)*5120 + rem];
        wl[rem*4 + l4] = __float2half(v);
    }
    __syncthreads();

    const float* fb = feats + (size_t)b*NN*FF*HW;
    for (int fc = 0; fc < 32; ++fc) {
        float acc[4][4];
        #pragma unroll
        for (int j = 0; j < 4; ++j) {
            #pragma unroll
            for (int l = 0; l < 4; ++l) acc[j][l] = 0.f;
        }
        #pragma unroll 4
        for (int n = 0; n < NN; ++n) {
            const int2 wv = *(const int2*)(wl + (n*HW + tid)*4);
            const __half2* h2 = (const __half2*)&wv;
            const float2 w01 = __half22float2(h2[0]);
            const float2 w23 = __half22float2(h2[1]);
            const float wlv[4] = {w01.x, w01.y, w23.x, w23.y};
            #pragma unroll
            for (int j = 0; j < 4; ++j) {
                const float v = fb[(size_t)(n*FF + fc*4 + j)*HW + tid];
                #pragma unroll
                for (int l = 0; l < 4; ++l) acc[j][l] = fmaf(v, wlv[l], acc[j][l]);
            }
        }
        // combine 4 neighboring hw lanes in-register
        #pragma unroll
        for (int j = 0; j < 4; ++j) {
            #pragma unroll
            for (int l = 0; l < 4; ++l) {
                float a = acc[j][l];
                a += __shfl_xor(a, 1, 64);
                a += __shfl_xor(a, 2, 64);
                acc[j][l] = a;
            }
        }
        if ((tid & 3) == 0) {
            float* rp = red + (tid >> 2) * 20;
            #pragma unroll
            for (int j = 0; j < 4; ++j) {
                #pragma unroll
                for (int l = 0; l < 4; ++l) rp[j*4 + l] = acc[j][l];
            }
        }
        __syncthreads();
        {   // stage 2: 16 groups x 16 outputs
            const int v = tid & 15, g = tid >> 4;
            float p = 0.f;
            #pragma unroll
            for (int i = 0; i < 4; ++i) p += red[(g*4 + i)*20 + v];
            red2[tid] = p;
        }
        __syncthreads();
        if (tid < 16) {
            float s = 0.f;
            #pragma unroll
            for (int g = 0; g < 16; ++g) s += red2[g*16 + tid];
            const int j = tid >> 2, l = tid & 3;
            gout[(size_t)(b*LL + l0 + l)*FF + fc*4 + j] = s;
        }
        __syncthreads();
    }
}

// ---------------------------------------------------------------------------
extern "C" void kernel_launch(void* const* d_in, const int* in_sizes, int n_in,
                              void* d_out, int out_size, void* d_ws, size_t ws_size,
                              hipStream_t stream)
{
    const float* bbox  = (const float*)d_in[0];
    const float* locs  = (const float*)d_in[1];
    const float* feats = (const float*)d_in[2];
    const float* over  = (const float*)d_in[3];
    const float* rays  = (const float*)d_in[4];
    const float* W1    = (const float*)d_in[5];
    const float* b1    = (const float*)d_in[6];
    const float* W2    = (const float*)d_in[7];
    const float* b2    = (const float*)d_in[8];
    const float* Wf    = (const float*)d_in[9];
    const float* bfp   = (const float*)d_in[10];
    const int B = in_sizes[0] / 4;
    float* ws  = (float*)d_ws;
    float* out = (float*)d_out;

    k1_pre<<<dim3(AA + B*NN + B*4 + 1), dim3(256), 0, stream>>>(
        rays, feats, over, W1, b1, W2, b2, Wf, bfp, ws, B);
    k2_geom<<<dim3((B*LL*NN + 255)/256), dim3(256), 0, stream>>>(bbox, locs, ws, B);
    k3_softmax<<<dim3(B*LL), dim3(256), 0, stream>>>(ws, out, B);
    k4_einsum<<<dim3(B*256), dim3(256), 0, stream>>>(
        feats, out + (size_t)B*LL*FF, out, B);
}

// Round 2
// 43.539 us; speedup vs baseline: 2.8193x; 2.8193x over previous
//
#include <hip/hip_runtime.h>
#include <hip/hip_fp16.h>
#include <math.h>

#define HH 8
#define WW 32
#define HW 256
#define NN 20
#define FF 128
#define LL 1024
#define AA 360
#define CO 64
#define KK 5120          // NN*HW
#define KS 8             // K splits
#define KC 640           // K per split
#define BM 32            // rows per block in k4
#define BK 64            // K per LDS step

// workspace offsets (in floats)
#define OFF_LPANO      (AA*HW)
#define OFF_OV(B)      (OFF_LPANO + (B)*NN*HW)
#define OFF_SCAL(B)    (OFF_OV(B) + (B)*LL*2)
#define OFF_BASE(B)    (OFF_SCAL(B) + 8)
#define OFF_IDX(B)     (OFF_BASE(B) + (B)*LL*NN)
#define OFF_BT(B)      (((OFF_IDX(B) + (B)*LL*NN + 7)/8)*8)      // f16 Bt [B][128][5120]
#define OFF_CP(B)      (OFF_BT(B) + (B)*FF*KK/2)                 // f32 partials [KS][B*LL][128]

typedef __attribute__((ext_vector_type(8))) _Float16 f16x8;
typedef __attribute__((ext_vector_type(4))) _Float16 f16x4;
typedef __attribute__((ext_vector_type(4))) float f32x4;

// ---------------------------------------------------------------------------
// K1: precompute Lray[360][256], Lpano[B*20][256], ov_stats[B*1024][2], scalars
// ---------------------------------------------------------------------------
__global__ __launch_bounds__(256)
void k1_pre(const float* __restrict__ rays, const float* __restrict__ feats,
            const float* __restrict__ overhead,
            const float* __restrict__ W1, const float* __restrict__ b1,
            const float* __restrict__ W2, const float* __restrict__ b2,
            const float* __restrict__ Wf, const float* __restrict__ bfp,
            float* __restrict__ ws, int B)
{
    const int bid = blockIdx.x, tid = threadIdx.x;
    const float wf0 = Wf[0], wf1 = Wf[1];

    if (bid < AA) {                       // ---- Lray for angle bid
        __shared__ float s[3*HW];
        for (int c = 0; c < 3; ++c) s[c*HW + tid] = rays[(bid*3 + c)*HW + tid];
        __syncthreads();
        const int h = tid >> 5, w = tid & 31;
        float c1 = 0.f, c2 = 0.f;
        #pragma unroll
        for (int c = 0; c < 3; ++c) {
            #pragma unroll
            for (int ky = 0; ky < 3; ++ky)
                #pragma unroll
                for (int kx = 0; kx < 3; ++kx)
                    c1 += W1[(1+c)*9 + ky*3 + kx] *
                          s[c*HW + (((h+ky+7)&7)<<5) + ((w+kx+31)&31)];
            #pragma unroll
            for (int ky = 0; ky < 5; ++ky)
                #pragma unroll
                for (int kx = 0; kx < 5; ++kx)
                    c2 += W2[(1+c)*25 + ky*5 + kx] *
                          s[c*HW + (((h+ky+6)&7)<<5) + ((w+kx+30)&31)];
        }
        ws[bid*HW + tid] = wf0*c1 + wf1*c2;
        return;
    }

    const int pb = bid - AA;
    if (pb < B*NN) {                      // ---- pano stats + conv -> Lpano
        __shared__ float p[2*HW];
        const float* fp = feats + (size_t)pb * FF * HW + tid;
        float mx = -INFINITY; double sm = 0.0;
        for (int f = 0; f < FF; ++f) {
            float v = fp[(size_t)f * HW];
            mx = fmaxf(mx, v); sm += (double)v;
        }
        p[tid]      = mx;
        p[HW + tid] = (float)(sm / 128.0);
        __syncthreads();
        const int h = tid >> 5, w = tid & 31;
        float c1 = 0.f, c2 = 0.f;
        #pragma unroll
        for (int c = 0; c < 2; ++c) {
            #pragma unroll
            for (int ky = 0; ky < 3; ++ky)
                #pragma unroll
                for (int kx = 0; kx < 3; ++kx)
                    c1 += W1[(4+c)*9 + ky*3 + kx] *
                          p[c*HW + (((h+ky+7)&7)<<5) + ((w+kx+31)&31)];
            #pragma unroll
            for (int ky = 0; ky < 5; ++ky)
                #pragma unroll
                for (int kx = 0; kx < 5; ++kx)
                    c2 += W2[(4+c)*25 + ky*5 + kx] *
                          p[c*HW + (((h+ky+6)&7)<<5) + ((w+kx+30)&31)];
        }
        ws[OFF_LPANO + pb*HW + tid] = wf0*c1 + wf1*c2;
        return;
    }

    const int ob = bid - AA - B*NN;
    if (ob < B*4) {                       // ---- overhead stats
        const int t = ob*256 + tid;       // t in [0, B*1024)
        const int b = t >> 10, l = t & 1023;
        const float* op = overhead + (size_t)b*CO*LL + l;
        float mx = -INFINITY; double sm = 0.0;
        for (int c = 0; c < CO; ++c) {
            float v = op[(size_t)c*LL];
            mx = fmaxf(mx, v); sm += (double)v;
        }
        ws[OFF_OV(B) + t*2]     = mx;
        ws[OFF_OV(B) + t*2 + 1] = (float)(sm / 64.0);
        return;
    }

    if (tid == 0) {                       // ---- scalar kernel-sums
        double s10=0, s16=0, s17=0, s20=0, s26=0, s27=0;
        for (int i = 0; i < 9;  ++i) { s10 += W1[i]; s16 += W1[54+i];  s17 += W1[63+i]; }
        for (int i = 0; i < 25; ++i) { s20 += W2[i]; s26 += W2[150+i]; s27 += W2[175+i]; }
        ws[OFF_SCAL(B)+0] = (float)(wf0*s10 + wf1*s20);            // Cd
        ws[OFF_SCAL(B)+1] = (float)(wf0*s16 + wf1*s26);            // Com
        ws[OFF_SCAL(B)+2] = (float)(wf0*s17 + wf1*s27);            // Cov
        ws[OFF_SCAL(B)+3] = wf0*b1[0] + wf1*b2[0] + bfp[0];        // Cb
    }
}

// ---------------------------------------------------------------------------
// K2: geometry (double, matches np f64 ref) -> idx[b,l,n], base[b,l,n]
// ---------------------------------------------------------------------------
__global__ __launch_bounds__(256)
void k2_geom(const float* __restrict__ bbox, const float* __restrict__ locs,
             float* __restrict__ ws, int B)
{
    const int t = blockIdx.x*256 + threadIdx.x;
    if (t >= B*LL*NN) return;
    const int b = t / (LL*NN), r = t % (LL*NN), l = r / NN, n = r % NN;
    const int iy = l >> 5, ix = l & 31;
    const double y0 = (double)bbox[b*4+0], x0 = (double)bbox[b*4+1];
    const double y1 = (double)bbox[b*4+2], x1 = (double)bbox[b*4+3];
    const double cy = y0 + (double)iy * (y1 - y0) / 31.0;
    const double cx = x0 + (double)ix * (x1 - x0) / 31.0;
    const double d0 = (double)locs[(b*NN+n)*2+0] - cy;
    const double d1 = (double)locs[(b*NN+n)*2+1] - cx;
    const double D  = sqrt(d0*d0 + d1*d1);
    double th = atan2(d1, d0);
    const double TWO_PI = 6.283185307179586476925286766559;
    th -= TWO_PI * floor(th / TWO_PI);                 // jnp.mod semantics
    const double deg = th * 57.295779513082320876798154814105;  // 180/pi
    int k = (int)llrint(deg);                          // round-half-even
    int idx = k % 360; if (idx < 0) idx += 360;

    const float Cd  = ws[OFF_SCAL(B)+0], Com = ws[OFF_SCAL(B)+1];
    const float Cov = ws[OFF_SCAL(B)+2], Cb  = ws[OFF_SCAL(B)+3];
    const int bl = b*LL + l;
    const float bv = (float)(Cd * D) + Com*ws[OFF_OV(B)+bl*2]
                   + Cov*ws[OFF_OV(B)+bl*2+1] + Cb;
    ws[OFF_BASE(B) + t] = bv;
    ((int*)(ws + OFF_IDX(B)))[t] = idx;
}

// ---------------------------------------------------------------------------
// K2b: permute feats [b][n][f][hw] f32 -> Bt [b][f][n*256+hw] f16
// ---------------------------------------------------------------------------
__global__ __launch_bounds__(256)
void k2b_bt(const float* __restrict__ feats, float* __restrict__ ws, int B)
{
    const int NG_PER_B = NN*FF*64;               // 4-wide groups per batch
    const int g = blockIdx.x*256 + threadIdx.x;
    if (g >= B*NG_PER_B) return;
    const int b = g / NG_PER_B;
    const int r = g - b*NG_PER_B;
    const int n = r / (FF*64);
    const int r2 = r % (FF*64);
    const int f = r2 >> 6;
    const int hw0 = (r2 & 63) << 2;
    const float4 v = *(const float4*)(feats + ((size_t)((b*NN + n)*FF + f))*HW + hw0);
    f16x4 h;
    h[0] = (_Float16)v.x; h[1] = (_Float16)v.y;
    h[2] = (_Float16)v.z; h[3] = (_Float16)v.w;
    _Float16* bt = (_Float16*)(ws + OFF_BT(B));
    *(f16x4*)(bt + ((size_t)(b*FF + f))*KK + n*HW + hw0) = h;
}

// ---------------------------------------------------------------------------
// K3: per-(b,l) softmax over (n,h,w), write weight output (f32)
// ---------------------------------------------------------------------------
__global__ __launch_bounds__(256)
void k3_softmax(const float* __restrict__ ws, float* __restrict__ out, int B)
{
    const int bid = blockIdx.x, tid = threadIdx.x;
    const int b = bid / LL;
    const float* Lray  = ws;
    const float* Lpano = ws + OFF_LPANO;
    const float* base  = ws + OFF_BASE(B) + (size_t)bid*NN;
    const int*   idxp  = (const int*)(ws + OFF_IDX(B)) + (size_t)bid*NN;

    __shared__ float sb[NN];
    __shared__ int   si[NN];
    __shared__ float sred[8];
    if (tid < NN) { sb[tid] = base[tid]; si[tid] = idxp[tid]; }
    __syncthreads();

    float lg[NN];
    float mx = -INFINITY;
    #pragma unroll
    for (int n = 0; n < NN; ++n) {
        lg[n] = sb[n] + Lray[si[n]*HW + tid] + Lpano[(b*NN+n)*HW + tid];
        mx = fmaxf(mx, lg[n]);
    }
    #pragma unroll
    for (int o = 32; o > 0; o >>= 1) mx = fmaxf(mx, __shfl_xor(mx, o, 64));
    if ((tid & 63) == 0) sred[tid >> 6] = mx;
    __syncthreads();
    mx = fmaxf(fmaxf(sred[0], sred[1]), fmaxf(sred[2], sred[3]));

    float sm = 0.f;
    #pragma unroll
    for (int n = 0; n < NN; ++n) { lg[n] = expf(lg[n] - mx); sm += lg[n]; }
    #pragma unroll
    for (int o = 32; o > 0; o >>= 1) sm += __shfl_xor(sm, o, 64);
    if ((tid & 63) == 0) sred[4 + (tid >> 6)] = sm;
    __syncthreads();
    const float inv = 1.0f / (sred[4] + sred[5] + sred[6] + sred[7]);

    float* wout = out + (size_t)B*LL*FF + (size_t)bid*NN*HW + tid;
    #pragma unroll
    for (int n = 0; n < NN; ++n) wout[n*HW] = lg[n] * inv;
}

// ---------------------------------------------------------------------------
// K4: split-K f16 MFMA GEMM: Cp[ks][b*LL+l][f] = sum_{k in chunk} W[l,k]*Bt[f,k]
//     BM=32 rows/block, full N=128, BK=64, XOR-swizzled LDS tiles.
// ---------------------------------------------------------------------------
__global__ __launch_bounds__(256)
void k4_gemm(const float* __restrict__ wbuf, const float* __restrict__ ws,
             float* __restrict__ cp, int B)
{
    __shared__ __align__(16) _Float16 As[BM*BK];     //  4 KB, swizzled
    __shared__ __align__(16) _Float16 Bs[FF*BK];     // 16 KB, swizzled
    const int x = blockIdx.x;
    const int ks = x & 7, mb = (x >> 3) & 31, b = x >> 8;
    const int l0 = mb * BM;
    const int kc0 = ks * KC;
    const int tid = threadIdx.x;
    const int wid = tid >> 6, lane = tid & 63, lr = lane & 15, lk = lane >> 4;

    const float*    Wb  = wbuf + ((size_t)(b*LL + l0))*KK;
    const _Float16* Btb = (const _Float16*)(ws + OFF_BT(B)) + (size_t)b*FF*KK;

    f32x4 acc[2][2] = {};

    // fragment LDS byte addresses (swizzle: byte ^= (row&7)<<4 within row)
    int aoff[2][2], boff[2][2];
    #pragma unroll
    for (int m = 0; m < 2; ++m)
        #pragma unroll
        for (int kk = 0; kk < 2; ++kk) {
            const int row = m*16 + lr;
            aoff[m][kk] = row*128 + ((kk*64 + lk*16) ^ ((row & 7) << 4));
        }
    #pragma unroll
    for (int n = 0; n < 2; ++n)
        #pragma unroll
        for (int kk = 0; kk < 2; ++kk) {
            const int row = wid*32 + n*16 + lr;
            boff[n][kk] = row*128 + ((kk*64 + lk*16) ^ ((row & 7) << 4));
        }

    // staging indices
    const int arow = tid >> 3, ac8 = tid & 7;
    const int adst = arow*128 + ((ac8*16) ^ ((arow & 7) << 4));

    char* AsB = (char*)As;
    char* BsB = (char*)Bs;

    for (int s = 0; s < KC/BK; ++s) {
        const int kc = kc0 + s*BK;
        // ---- stage A: 32x64 f32 -> f16, swizzled
        {
            const float* src = Wb + (size_t)arow*KK + kc + ac8*8;
            const float4 v0 = *(const float4*)src;
            const float4 v1 = *(const float4*)(src + 4);
            f16x8 h;
            h[0] = (_Float16)v0.x; h[1] = (_Float16)v0.y;
            h[2] = (_Float16)v0.z; h[3] = (_Float16)v0.w;
            h[4] = (_Float16)v1.x; h[5] = (_Float16)v1.y;
            h[6] = (_Float16)v1.z; h[7] = (_Float16)v1.w;
            *(f16x8*)(AsB + adst) = h;
        }
        // ---- stage B: 128x64 f16, swizzled
        #pragma unroll
        for (int c = 0; c < 4; ++c) {
            const int e = c*256 + tid;
            const int row = e >> 3, c8 = e & 7;
            const f16x8 h = *(const f16x8*)(Btb + (size_t)row*KK + kc + c8*8);
            const int dst = row*128 + ((c8*16) ^ ((row & 7) << 4));
            *(f16x8*)(BsB + dst) = h;
        }
        __syncthreads();
        // ---- compute: 8 MFMA
        #pragma unroll
        for (int kk = 0; kk < 2; ++kk) {
            const f16x8 a0 = *(const f16x8*)(AsB + aoff[0][kk]);
            const f16x8 a1 = *(const f16x8*)(AsB + aoff[1][kk]);
            const f16x8 b0 = *(const f16x8*)(BsB + boff[0][kk]);
            const f16x8 b1 = *(const f16x8*)(BsB + boff[1][kk]);
            acc[0][0] = __builtin_amdgcn_mfma_f32_16x16x32_f16(a0, b0, acc[0][0], 0, 0, 0);
            acc[0][1] = __builtin_amdgcn_mfma_f32_16x16x32_f16(a0, b1, acc[0][1], 0, 0, 0);
            acc[1][0] = __builtin_amdgcn_mfma_f32_16x16x32_f16(a1, b0, acc[1][0], 0, 0, 0);
            acc[1][1] = __builtin_amdgcn_mfma_f32_16x16x32_f16(a1, b1, acc[1][1], 0, 0, 0);
        }
        __syncthreads();
    }

    // ---- write partials: Cp[ks][b*LL + l][f]
    float* cpb = cp + ((size_t)ks*B*LL + (size_t)b*LL + l0)*FF;
    #pragma unroll
    for (int m = 0; m < 2; ++m)
        #pragma unroll
        for (int n = 0; n < 2; ++n) {
            const int col = wid*32 + n*16 + lr;
            #pragma unroll
            for (int r = 0; r < 4; ++r) {
                const int row = m*16 + lk*4 + r;
                cpb[(size_t)row*FF + col] = acc[m][n][r];
            }
        }
}

// ---------------------------------------------------------------------------
// K5: reduce split-K partials -> grid_feats
// ---------------------------------------------------------------------------
__global__ __launch_bounds__(256)
void k5_reduce(const float* __restrict__ cp, float* __restrict__ gout, int B)
{
    const size_t total = (size_t)B*LL*FF;
    const size_t i = ((size_t)blockIdx.x*256 + threadIdx.x)*4;
    if (i >= total) return;
    float4 s = {0.f, 0.f, 0.f, 0.f};
    #pragma unroll
    for (int ks = 0; ks < KS; ++ks) {
        const float4 v = *(const float4*)(cp + ks*total + i);
        s.x += v.x; s.y += v.y; s.z += v.z; s.w += v.w;
    }
    *(float4*)(gout + i) = s;
}

// ---------------------------------------------------------------------------
extern "C" void kernel_launch(void* const* d_in, const int* in_sizes, int n_in,
                              void* d_out, int out_size, void* d_ws, size_t ws_size,
                              hipStream_t stream)
{
    const float* bbox  = (const float*)d_in[0];
    const float* locs  = (const float*)d_in[1];
    const float* feats = (const float*)d_in[2];
    const float* over  = (const float*)d_in[3];
    const float* rays  = (const float*)d_in[4];
    const float* W1    = (const float*)d_in[5];
    const float* b1    = (const float*)d_in[6];
    const float* W2    = (const float*)d_in[7];
    const float* b2    = (const float*)d_in[8];
    const float* Wf    = (const float*)d_in[9];
    const float* bfp   = (const float*)d_in[10];
    const int B = in_sizes[0] / 4;
    float* ws  = (float*)d_ws;
    float* out = (float*)d_out;
    float* wout = out + (size_t)B*LL*FF;           // f32 weight output region
    float* cp   = ws + OFF_CP(B);

    k1_pre<<<dim3(AA + B*NN + B*4 + 1), dim3(256), 0, stream>>>(
        rays, feats, over, W1, b1, W2, b2, Wf, bfp, ws, B);
    k2_geom<<<dim3((B*LL*NN + 255)/256), dim3(256), 0, stream>>>(bbox, locs, ws, B);
    k2b_bt<<<dim3(B*NN*FF*64/256), dim3(256), 0, stream>>>(feats, ws, B);
    k3_softmax<<<dim3(B*LL), dim3(256), 0, stream>>>(ws, out, B);
    k4_gemm<<<dim3(B*32*KS), dim3(256), 0, stream>>>(wout, ws, cp, B);
    k5_reduce<<<dim3((B*LL*FF/4 + 255)/256), dim3(256), 0, stream>>>(cp, out, B);
}